// Round 2
// baseline (327.730 us; speedup 1.0000x reference)
//
#include <hip/hip_runtime.h>

// NarrativeClassificationLoss: single streaming pass, barrier-free main loop.
// Narrative phase and sub phase decoupled (sub re-reads narr inputs from
// L1/L2 instead of LDS staging). Fast native exp/log. Per-column partial
// sums (linear decomposition in pos_weight), tiny finalize kernel.
//
// B=16384, N_NARR=128, N_SUB=1024, K=8, GAMMA=2, weights (1,1,0.5).

#define BDIM 256
#define NROWS 16384
#define NNARR 128
#define NSUB 1024
#define ROWS_PER_BLOCK 16
#define NBLOCKS (NROWS / ROWS_PER_BLOCK)   // 1024

// workspace float layout
#define WS_AN    0      // [128]  sum_b y*sp(-x)            (narrative)
#define WS_CN    128    // [128]  sum_b (1-y)*sp(x)
#define WS_NSUM  256    // [128]  column sums of narrative labels
#define WS_AS    384    // [1024] sum_b pos*y*sp(-x)        (subnarrative)
#define WS_CS    1408   // [1024] sum_b pos*(1-y)*sp(x)
#define WS_SSUM  2432   // [1024] column sums of sub labels (unmasked)
#define WS_FN    3456   // focal narrative sum
#define WS_FS    3457   // focal subnarrative sum
#define WS_HIER  3458   // hierarchy sum
#define WS_FLOATS 3459

// softplus(x), softplus(-x), sigmoid(x) via native v_exp/v_log/v_rcp.
// __logf(1+e) vs log1pf: abs err <= ~1e-7, irrelevant after /2M mean.
__device__ __forceinline__ void bce_pieces(float x, float& sp_p, float& sp_m, float& sig) {
    float a = fabsf(x);
    float e = __expf(-a);              // exp(-|x|) in (0,1]
    float l = __logf(1.0f + e);        // ~log1p(e)
    sp_p = fmaxf(x, 0.0f) + l;
    sp_m = sp_p - x;
    float inv = __builtin_amdgcn_rcpf(1.0f + e);
    sig = (x >= 0.0f) ? inv : e * inv;
}

__global__ __launch_bounds__(BDIM) void ncl_main(
    const float* __restrict__ nlog, const float* __restrict__ slog,
    const int*   __restrict__ nlab, const int*   __restrict__ slab,
    float* __restrict__ ws)
{
    __shared__ float nred[BDIM][12];   // 12 KB, used once at the end

    const int t    = threadIdx.x;
    const int r0   = blockIdx.x * ROWS_PER_BLOCK;
    const int g    = t >> 1;           // sub group: cols 4t..4t+3 lie in group t/2

    float fn = 0.f, fs = 0.f, hier = 0.f;

    // ---- narrative phase: 2 iters x (8 rows x 128 cols) via float4 ----
    // thread t owns cols 4*(t&31)+j; row within slab = t>>5.
    float An[4] = {0,0,0,0}, Cn[4] = {0,0,0,0}, ns[4] = {0,0,0,0};
    #pragma unroll
    for (int i = 0; i < 2; ++i) {
        const int base = (r0 + 8 * i) * NNARR + 4 * t;
        const float4 xs = *(const float4*)(nlog + base);
        const int4   ys = *(const int4*)  (nlab + base);
        const float xv[4] = {xs.x, xs.y, xs.z, xs.w};
        const float yv[4] = {(float)ys.x, (float)ys.y, (float)ys.z, (float)ys.w};
        #pragma unroll
        for (int j = 0; j < 4; ++j) {
            float sp_p, sp_m, sig;
            bce_pieces(xv[j], sp_p, sp_m, sig);
            float y = yv[j];
            An[j] += y * sp_m;
            Cn[j] += (1.0f - y) * sp_p;
            ns[j] += y;
            float om = 1.0f - sig;
            fn += om * om * y * (-sp_m);   // log_sigmoid(x) = -softplus(-x)
        }
    }

    // ---- sub phase: barrier-free, 16 rows, thread owns cols 4t..4t+3 ----
    float As[4] = {0,0,0,0}, Cs[4] = {0,0,0,0}, ss[4] = {0,0,0,0};
    #pragma unroll 4
    for (int i = 0; i < ROWS_PER_BLOCK; ++i) {
        const int r = r0 + i;
        // narrative value for this group, from L1/L2 (2 adjacent threads share)
        const float  nx   = nlog[r * NNARR + g];
        const float  posv = (float)nlab[r * NNARR + g];
        const float4 xs = *(const float4*)(slog + r * NSUB + 4 * t);
        const int4   ys = *(const int4*)  (slab + r * NSUB + 4 * t);

        float nsig;
        {
            float a = fabsf(nx);
            float e = __expf(-a);
            float inv = __builtin_amdgcn_rcpf(1.0f + e);
            nsig = (nx >= 0.0f) ? inv : e * inv;
        }

        const float xv[4] = {xs.x, xs.y, xs.z, xs.w};
        const float yv[4] = {(float)ys.x, (float)ys.y, (float)ys.z, (float)ys.w};
        float mymax = 0.0f;
        #pragma unroll
        for (int j = 0; j < 4; ++j) {
            float sp_p, sp_m, sig;
            bce_pieces(xv[j], sp_p, sp_m, sig);
            float y = yv[j];
            As[j] += posv * y * sp_m;
            Cs[j] += posv * (1.0f - y) * sp_p;
            ss[j] += y;
            float om = 1.0f - sig;
            fs += om * om * y * (-sp_m);
            mymax = fmaxf(mymax, sig);
        }
        // group max over 8 cols = pair of adjacent threads
        float gmax = fmaxf(mymax, __shfl_xor(mymax, 1, 64));
        if ((t & 1) == 0)
            hier += fmaxf(gmax - nsig, 0.0f) * posv;
    }

    // ---- sub column partials: thread uniquely owns its 4 cols in-block ----
    #pragma unroll
    for (int j = 0; j < 4; ++j) {
        atomicAdd(&ws[WS_AS   + 4 * t + j], As[j]);
        atomicAdd(&ws[WS_CS   + 4 * t + j], Cs[j]);
        atomicAdd(&ws[WS_SSUM + 4 * t + j], ss[j]);
    }

    // ---- narrative fold: 8 threads share each col quad (t & 31) ----
    #pragma unroll
    for (int j = 0; j < 4; ++j) {
        nred[t][j]     = An[j];
        nred[t][4 + j] = Cn[j];
        nred[t][8 + j] = ns[j];
    }
    __syncthreads();
    if (t < 32) {
        float a[12];
        #pragma unroll
        for (int j = 0; j < 12; ++j) a[j] = nred[t][j];
        #pragma unroll
        for (int w = 1; w < 8; ++w)
            #pragma unroll
            for (int j = 0; j < 12; ++j) a[j] += nred[t + 32 * w][j];
        #pragma unroll
        for (int j = 0; j < 4; ++j) {
            atomicAdd(&ws[WS_AN   + 4 * t + j], a[j]);
            atomicAdd(&ws[WS_CN   + 4 * t + j], a[4 + j]);
            atomicAdd(&ws[WS_NSUM + 4 * t + j], a[8 + j]);
        }
    }

    // ---- scalar partials: wave shuffle reduce, one atomic per wave ----
    #pragma unroll
    for (int off = 32; off; off >>= 1) {
        fn   += __shfl_down(fn,   off, 64);
        fs   += __shfl_down(fs,   off, 64);
        hier += __shfl_down(hier, off, 64);
    }
    if ((t & 63) == 0) {
        atomicAdd(&ws[WS_FN],   fn);
        atomicAdd(&ws[WS_FS],   fs);
        atomicAdd(&ws[WS_HIER], hier);
    }
}

__global__ __launch_bounds__(1024) void ncl_finalize(const float* __restrict__ ws,
                                                     float* __restrict__ out)
{
    __shared__ float sr[3][16];
    const int t = threadIdx.x;
    const float Bf = (float)NROWS;

    // sub column t: combine with clamped pos_weight
    float s_sub = ws[WS_SSUM + t];
    float spw   = fminf(fmaxf((Bf - s_sub) / (s_sub + 1e-6f), 1.0f), 50.0f);
    float sub_part = spw * ws[WS_AS + t] + ws[WS_CS + t];

    float narr_part = 0.f, valid_part = 0.f;
    if (t < NNARR) {
        float s = ws[WS_NSUM + t];
        float npw = fminf(fmaxf((Bf - s) / (s + 1e-6f), 1.0f), 50.0f);
        narr_part  = npw * ws[WS_AN + t] + ws[WS_CN + t];
        valid_part = s;
    }

    #pragma unroll
    for (int off = 32; off; off >>= 1) {
        sub_part   += __shfl_down(sub_part,   off, 64);
        narr_part  += __shfl_down(narr_part,  off, 64);
        valid_part += __shfl_down(valid_part, off, 64);
    }
    if ((t & 63) == 0) {
        int w = t >> 6;
        sr[0][w] = sub_part; sr[1][w] = narr_part; sr[2][w] = valid_part;
    }
    __syncthreads();
    if (t == 0) {
        float sub_tot = 0.f, narr_tot = 0.f, valid = 0.f;
        #pragma unroll
        for (int i = 0; i < 16; ++i) { sub_tot += sr[0][i]; narr_tot += sr[1][i]; valid += sr[2][i]; }

        float narrative_loss = narr_tot / (Bf * (float)NNARR);
        float sub_loss = (valid > 0.0f) ? (sub_tot * (1.0f / 8.0f)) / fmaxf(valid, 1.0f) : 0.0f;
        float nf = ws[WS_FN] / (Bf * (float)NNARR);
        float sf = ws[WS_FS] / (Bf * (float)NSUB);
        float hier_loss = ws[WS_HIER] / Bf;

        out[0] = (narrative_loss - 0.1f * nf)
               + (sub_loss       - 0.1f * sf)
               + 0.5f * hier_loss;
    }
}

extern "C" void kernel_launch(void* const* d_in, const int* in_sizes, int n_in,
                              void* d_out, int out_size, void* d_ws, size_t ws_size,
                              hipStream_t stream) {
    const float* nlog = (const float*)d_in[0];
    const float* slog = (const float*)d_in[1];
    const int*   nlab = (const int*)d_in[2];
    const int*   slab = (const int*)d_in[3];
    float* ws  = (float*)d_ws;
    float* out = (float*)d_out;

    // workspace is re-poisoned to 0xAA before every call — zero the accumulators
    hipMemsetAsync(ws, 0, WS_FLOATS * sizeof(float), stream);

    ncl_main<<<NBLOCKS, BDIM, 0, stream>>>(nlog, slog, nlab, slab, ws);
    ncl_finalize<<<1, 1024, 0, stream>>>(ws, out);
}

// Round 3
// 230.451 us; speedup vs baseline: 1.4221x; 1.4221x over previous
//
#include <hip/hip_runtime.h>

// NarrativeClassificationLoss — v3.
// R2 post-mortem: kernel was bound by ~3.55M atomicAdds onto 108 cache
// lines (~15.7 cyc per same-line RMW, write-through = 55 MB HBM writes).
// v3: 256 fat blocks, LDS fold, one PRIVATE partial-table copy per block
// (plain stores, no contention), then a small reduce kernel + finalize.
//
// B=16384, N_NARR=128, N_SUB=1024, K=8, GAMMA=2, weights (1,1,0.5).

#define BDIM 1024
#define NROWS 16384
#define NNARR 128
#define NSUB 1024
#define ROWS_PER_BLOCK 64
#define NBLOCKS (NROWS / ROWS_PER_BLOCK)   // 256

// per-copy table layout (floats)
#define WS_AN    0      // [128]  sum_b y*sp(-x)            (narrative)
#define WS_CN    128    // [128]  sum_b (1-y)*sp(x)
#define WS_NSUM  256    // [128]  col sums of narrative labels
#define WS_AS    384    // [1024] sum_b pos*y*sp(-x)        (subnarrative)
#define WS_CS    1408   // [1024] sum_b pos*(1-y)*sp(x)
#define WS_SSUM  2432   // [1024] col sums of sub labels
#define WS_FN    3456   // focal narrative sum
#define WS_FS    3457   // focal subnarrative sum
#define WS_HIER  3458   // hierarchy sum
#define WS_FLOATS 3459
#define CSTRIDE  3472   // copy stride in floats (16B aligned)

__device__ __forceinline__ void bce_pieces(float x, float& sp_p, float& sp_m, float& sig) {
    float a = fabsf(x);
    float e = __expf(-a);              // exp(-|x|) in (0,1]
    float l = __logf(1.0f + e);        // ~log1p(e); err ~1e-7, fine after /2M
    sp_p = fmaxf(x, 0.0f) + l;
    sp_m = sp_p - x;
    float inv = __builtin_amdgcn_rcpf(1.0f + e);
    sig = (x >= 0.0f) ? inv : e * inv;
}

__device__ __forceinline__ void emit(float* dst, float v, int excl) {
    if (excl) *dst = v; else atomicAdd(dst, v);
}

__global__ __launch_bounds__(BDIM) void ncl_main(
    const float* __restrict__ nlog, const float* __restrict__ slog,
    const int*   __restrict__ nlab, const int*   __restrict__ slab,
    float* __restrict__ ws, int ncopies, int excl)
{
    __shared__ float sred[BDIM][13];   // 53 KB fold buffer (padded stride)
    __shared__ float ssc[16][3];       // per-wave scalar partials

    const int t  = threadIdx.x;
    const int r0 = blockIdx.x * ROWS_PER_BLOCK;
    float* const cw = ws + (size_t)(blockIdx.x % ncopies) * CSTRIDE;

    float fn = 0.f, fs = 0.f, hier = 0.f;

    // ---- narrative phase: 64 rows x 128 cols = 2048 float4 quads ----
    float An[4] = {0,0,0,0}, Cn[4] = {0,0,0,0}, ns[4] = {0,0,0,0};
    #pragma unroll
    for (int i = 0; i < 2; ++i) {
        const int base = r0 * NNARR + 4 * (i * BDIM + t);
        const float4 xs = *(const float4*)(nlog + base);
        const int4   ys = *(const int4*)  (nlab + base);
        const float xv[4] = {xs.x, xs.y, xs.z, xs.w};
        const float yv[4] = {(float)ys.x, (float)ys.y, (float)ys.z, (float)ys.w};
        #pragma unroll
        for (int j = 0; j < 4; ++j) {
            float sp_p, sp_m, sig;
            bce_pieces(xv[j], sp_p, sp_m, sig);
            float y = yv[j];
            An[j] += y * sp_m;
            Cn[j] += (1.0f - y) * sp_p;
            ns[j] += y;
            float om = 1.0f - sig;
            fn += om * om * y * (-sp_m);   // log_sigmoid(x) = -softplus(-x)
        }
    }

    // fold narrative partials: 32 threads share col-quad (t & 31)
    #pragma unroll
    for (int j = 0; j < 4; ++j) {
        sred[t][j] = An[j]; sred[t][4 + j] = Cn[j]; sred[t][8 + j] = ns[j];
    }
    __syncthreads();
    if (t < 32) {
        float a[12];
        #pragma unroll
        for (int j = 0; j < 12; ++j) a[j] = sred[t][j];
        for (int s = 1; s < 32; ++s)
            #pragma unroll
            for (int j = 0; j < 12; ++j) a[j] += sred[t + 32 * s][j];
        #pragma unroll
        for (int j = 0; j < 4; ++j) {
            emit(cw + WS_AN   + 4 * t + j, a[j],     excl);
            emit(cw + WS_CN   + 4 * t + j, a[4 + j], excl);
            emit(cw + WS_NSUM + 4 * t + j, a[8 + j], excl);
        }
    }
    __syncthreads();   // fold reads done; sred reusable

    // ---- sub phase: 4 slabs x 16 rows; thread owns cols 4u..4u+3 ----
    const int sl = t >> 8;
    const int u  = t & 255;
    const int g  = u >> 1;             // narrative group of these 4 cols
    float As[4] = {0,0,0,0}, Cs[4] = {0,0,0,0}, ss[4] = {0,0,0,0};
    #pragma unroll 4
    for (int i = 0; i < 16; ++i) {
        const int r = r0 + sl * 16 + i;
        const float  nx   = nlog[r * NNARR + g];
        const float  posv = (float)nlab[r * NNARR + g];
        const float4 xs = *(const float4*)(slog + r * NSUB + 4 * u);
        const int4   ys = *(const int4*)  (slab + r * NSUB + 4 * u);

        float nsig;
        {
            float a = fabsf(nx);
            float e = __expf(-a);
            float inv = __builtin_amdgcn_rcpf(1.0f + e);
            nsig = (nx >= 0.0f) ? inv : e * inv;
        }

        const float xv[4] = {xs.x, xs.y, xs.z, xs.w};
        const float yv[4] = {(float)ys.x, (float)ys.y, (float)ys.z, (float)ys.w};
        float mymax = 0.0f;
        #pragma unroll
        for (int j = 0; j < 4; ++j) {
            float sp_p, sp_m, sig;
            bce_pieces(xv[j], sp_p, sp_m, sig);
            float y = yv[j];
            As[j] += posv * y * sp_m;
            Cs[j] += posv * (1.0f - y) * sp_p;
            ss[j] += y;
            float om = 1.0f - sig;
            fs += om * om * y * (-sp_m);
            mymax = fmaxf(mymax, sig);
        }
        // group max over 8 cols = adjacent lane pair
        float gmax = fmaxf(mymax, __shfl_xor(mymax, 1, 64));
        if ((u & 1) == 0)
            hier += fmaxf(gmax - nsig, 0.0f) * posv;
    }

    // per-wave scalar reduce
    #pragma unroll
    for (int off = 32; off; off >>= 1) {
        fn   += __shfl_down(fn,   off, 64);
        fs   += __shfl_down(fs,   off, 64);
        hier += __shfl_down(hier, off, 64);
    }
    if ((t & 63) == 0) {
        int w = t >> 6;
        ssc[w][0] = fn; ssc[w][1] = fs; ssc[w][2] = hier;
    }

    // fold sub partials: 4 slabs share col set u
    #pragma unroll
    for (int j = 0; j < 4; ++j) {
        sred[t][j] = As[j]; sred[t][4 + j] = Cs[j]; sred[t][8 + j] = ss[j];
    }
    __syncthreads();
    if (t < 256) {
        float b[12];
        #pragma unroll
        for (int j = 0; j < 12; ++j) b[j] = sred[t][j];
        #pragma unroll
        for (int s = 1; s < 4; ++s)
            #pragma unroll
            for (int j = 0; j < 12; ++j) b[j] += sred[t + 256 * s][j];
        #pragma unroll
        for (int j = 0; j < 4; ++j) {
            emit(cw + WS_AS   + 4 * t + j, b[j],     excl);
            emit(cw + WS_CS   + 4 * t + j, b[4 + j], excl);
            emit(cw + WS_SSUM + 4 * t + j, b[8 + j], excl);
        }
    }
    if (t == 0) {
        float a = 0.f, b = 0.f, c = 0.f;
        #pragma unroll
        for (int w = 0; w < 16; ++w) { a += ssc[w][0]; b += ssc[w][1]; c += ssc[w][2]; }
        emit(cw + WS_FN,   a, excl);
        emit(cw + WS_FS,   b, excl);
        emit(cw + WS_HIER, c, excl);
    }
}

// sum the per-block copies into one table
__global__ __launch_bounds__(256) void ncl_reduce(const float* __restrict__ ws,
                                                  float* __restrict__ red, int ncopies)
{
    const int e = blockIdx.x * 256 + threadIdx.x;
    if (e >= WS_FLOATS) return;
    float s = 0.f;
    #pragma unroll 4
    for (int c = 0; c < ncopies; ++c)
        s += ws[(size_t)c * CSTRIDE + e];
    red[e] = s;
}

__global__ __launch_bounds__(1024) void ncl_finalize(const float* __restrict__ ws,
                                                     float* __restrict__ out)
{
    __shared__ float sr[3][16];
    const int t = threadIdx.x;
    const float Bf = (float)NROWS;

    float s_sub = ws[WS_SSUM + t];
    float spw   = fminf(fmaxf((Bf - s_sub) / (s_sub + 1e-6f), 1.0f), 50.0f);
    float sub_part = spw * ws[WS_AS + t] + ws[WS_CS + t];

    float narr_part = 0.f, valid_part = 0.f;
    if (t < NNARR) {
        float s = ws[WS_NSUM + t];
        float npw = fminf(fmaxf((Bf - s) / (s + 1e-6f), 1.0f), 50.0f);
        narr_part  = npw * ws[WS_AN + t] + ws[WS_CN + t];
        valid_part = s;
    }

    #pragma unroll
    for (int off = 32; off; off >>= 1) {
        sub_part   += __shfl_down(sub_part,   off, 64);
        narr_part  += __shfl_down(narr_part,  off, 64);
        valid_part += __shfl_down(valid_part, off, 64);
    }
    if ((t & 63) == 0) {
        int w = t >> 6;
        sr[0][w] = sub_part; sr[1][w] = narr_part; sr[2][w] = valid_part;
    }
    __syncthreads();
    if (t == 0) {
        float sub_tot = 0.f, narr_tot = 0.f, valid = 0.f;
        #pragma unroll
        for (int i = 0; i < 16; ++i) { sub_tot += sr[0][i]; narr_tot += sr[1][i]; valid += sr[2][i]; }

        float narrative_loss = narr_tot / (Bf * (float)NNARR);
        float sub_loss = (valid > 0.0f) ? (sub_tot * (1.0f / 8.0f)) / fmaxf(valid, 1.0f) : 0.0f;
        float nf = ws[WS_FN] / (Bf * (float)NNARR);
        float sf = ws[WS_FS] / (Bf * (float)NSUB);
        float hier_loss = ws[WS_HIER] / Bf;

        out[0] = (narrative_loss - 0.1f * nf)
               + (sub_loss       - 0.1f * sf)
               + 0.5f * hier_loss;
    }
}

extern "C" void kernel_launch(void* const* d_in, const int* in_sizes, int n_in,
                              void* d_out, int out_size, void* d_ws, size_t ws_size,
                              hipStream_t stream) {
    const float* nlog = (const float*)d_in[0];
    const float* slog = (const float*)d_in[1];
    const int*   nlab = (const int*)d_in[2];
    const int*   slab = (const int*)d_in[3];
    float* ws  = (float*)d_ws;
    float* out = (float*)d_out;

    // one private copy per block if ws allows; else shared copies + atomics
    long avail = (long)(ws_size / 4) - WS_FLOATS;
    int ncopies = (int)(avail / CSTRIDE);
    if (ncopies > NBLOCKS) ncopies = NBLOCKS;
    int excl = (ncopies == NBLOCKS) ? 1 : 0;
    float* red;
    if (ncopies < 1) { ncopies = 1; excl = 0; red = ws; }   // alias fallback
    else             { red = ws + (size_t)ncopies * CSTRIDE; }

    if (!excl)
        hipMemsetAsync(ws, 0, (size_t)ncopies * CSTRIDE * sizeof(float), stream);

    ncl_main<<<NBLOCKS, BDIM, 0, stream>>>(nlog, slog, nlab, slab, ws, ncopies, excl);
    ncl_reduce<<<(WS_FLOATS + 255) / 256, 256, 0, stream>>>(ws, red, ncopies);
    ncl_finalize<<<1, 1024, 0, stream>>>(red, out);
}

// Round 4
// 192.666 us; speedup vs baseline: 1.7010x; 1.1961x over previous
//
#include <hip/hip_runtime.h>

// NarrativeClassificationLoss — v4.
// R3 post-mortem: __launch_bounds__(1024) capped VGPR at 64 -> scratch
// spills (WRITE_SIZE 13.2 MB vs 3.55 MB of real stores; VALUBusy 19%).
// v4: 256-thread blocks (<=128 VGPR, no spill), 1024 blocks x 16 rows,
// per-block private partial tables written with plain float4 stores,
// two-stage parallel reduce, finalize.
//
// B=16384, N_NARR=128, N_SUB=1024, K=8, GAMMA=2, weights (1,1,0.5).

#define BDIM 256
#define NROWS 16384
#define NNARR 128
#define NSUB 1024
#define ROWS_PER_BLOCK 16
#define NBLOCKS (NROWS / ROWS_PER_BLOCK)   // 1024

// per-copy table layout (floats)
#define WS_AN    0      // [128]  sum_b y*sp(-x)            (narrative)
#define WS_CN    128    // [128]  sum_b (1-y)*sp(x)
#define WS_NSUM  256    // [128]  col sums of narrative labels
#define WS_AS    384    // [1024] sum_b pos*y*sp(-x)        (subnarrative)
#define WS_CS    1408   // [1024] sum_b pos*(1-y)*sp(x)
#define WS_SSUM  2432   // [1024] col sums of sub labels
#define WS_FN    3456   // focal narrative sum
#define WS_FS    3457   // focal subnarrative sum
#define WS_HIER  3458   // hierarchy sum
#define WS_FLOATS 3459
#define CSTRIDE  3472   // copy stride in floats (16B aligned)
#define NCHUNK_MAX 32   // reduce stage1 fan-in slots

__device__ __forceinline__ void bce_pieces(float x, float& sp_p, float& sp_m, float& sig) {
    float a = fabsf(x);
    float e = __expf(-a);              // exp(-|x|) in (0,1]
    float l = __logf(1.0f + e);        // ~log1p(e); err ~1e-7, fine after /2M
    sp_p = fmaxf(x, 0.0f) + l;
    sp_m = sp_p - x;
    float inv = __builtin_amdgcn_rcpf(1.0f + e);
    sig = (x >= 0.0f) ? inv : e * inv;
}

__device__ __forceinline__ void emit4(float* dst, float a, float b, float c, float d, int excl) {
    if (excl) {
        *(float4*)dst = make_float4(a, b, c, d);
    } else {
        atomicAdd(dst + 0, a); atomicAdd(dst + 1, b);
        atomicAdd(dst + 2, c); atomicAdd(dst + 3, d);
    }
}

__global__ __launch_bounds__(BDIM, 4) void ncl_main(
    const float* __restrict__ nlog, const float* __restrict__ slog,
    const int*   __restrict__ nlab, const int*   __restrict__ slab,
    float* __restrict__ ws, int ncopies, int excl)
{
    __shared__ float sred[BDIM][13];   // 13.3 KB narrative fold buffer
    __shared__ float ssc[4][3];        // per-wave scalar partials

    const int t  = threadIdx.x;
    const int r0 = blockIdx.x * ROWS_PER_BLOCK;
    float* const cw = ws + (size_t)(blockIdx.x % ncopies) * CSTRIDE;

    float fn = 0.f, fs = 0.f, hier = 0.f;

    // ---- narrative phase: 16 rows x 128 cols = 512 float4 quads ----
    // iter i: quad q = i*256+t; col-quad q&31 (same for both i), row q>>5.
    {
        float An[4] = {0,0,0,0}, Cn[4] = {0,0,0,0}, ns[4] = {0,0,0,0};
        #pragma unroll
        for (int i = 0; i < 2; ++i) {
            const int base = r0 * NNARR + 4 * (i * BDIM + t);
            const float4 xs = *(const float4*)(nlog + base);
            const int4   ys = *(const int4*)  (nlab + base);
            const float xv[4] = {xs.x, xs.y, xs.z, xs.w};
            const float yv[4] = {(float)ys.x, (float)ys.y, (float)ys.z, (float)ys.w};
            #pragma unroll
            for (int j = 0; j < 4; ++j) {
                float sp_p, sp_m, sig;
                bce_pieces(xv[j], sp_p, sp_m, sig);
                float y = yv[j];
                An[j] += y * sp_m;
                Cn[j] += (1.0f - y) * sp_p;
                ns[j] += y;
                float om = 1.0f - sig;
                fn += om * om * y * (-sp_m);   // log_sigmoid(x) = -softplus(-x)
            }
        }
        // fold: 8 threads (t, t+32, ..., t+224) share col-quad t&31
        #pragma unroll
        for (int j = 0; j < 4; ++j) {
            sred[t][j] = An[j]; sred[t][4 + j] = Cn[j]; sred[t][8 + j] = ns[j];
        }
    }
    __syncthreads();
    if (t < 32) {
        float a[12];
        #pragma unroll
        for (int j = 0; j < 12; ++j) a[j] = sred[t][j];
        #pragma unroll
        for (int s = 1; s < 8; ++s)
            #pragma unroll
            for (int j = 0; j < 12; ++j) a[j] += sred[t + 32 * s][j];
        emit4(cw + WS_AN   + 4 * t, a[0], a[1], a[2],  a[3],  excl);
        emit4(cw + WS_CN   + 4 * t, a[4], a[5], a[6],  a[7],  excl);
        emit4(cw + WS_NSUM + 4 * t, a[8], a[9], a[10], a[11], excl);
    }
    // sred not used again; ssc is a separate array -> no barrier needed here.

    // ---- sub phase: 16 rows; thread owns cols 4t..4t+3 (group g = t>>1) ----
    const int g = t >> 1;
    float As[4] = {0,0,0,0}, Cs[4] = {0,0,0,0}, ss[4] = {0,0,0,0};
    #pragma unroll 4
    for (int i = 0; i < ROWS_PER_BLOCK; ++i) {
        const int r = r0 + i;
        const float  nx   = nlog[r * NNARR + g];
        const float  posv = (float)nlab[r * NNARR + g];
        const float4 xs = *(const float4*)(slog + r * NSUB + 4 * t);
        const int4   ys = *(const int4*)  (slab + r * NSUB + 4 * t);

        float nsig;
        {
            float a = fabsf(nx);
            float e = __expf(-a);
            float inv = __builtin_amdgcn_rcpf(1.0f + e);
            nsig = (nx >= 0.0f) ? inv : e * inv;
        }

        const float xv[4] = {xs.x, xs.y, xs.z, xs.w};
        const float yv[4] = {(float)ys.x, (float)ys.y, (float)ys.z, (float)ys.w};
        float mymax = 0.0f;
        #pragma unroll
        for (int j = 0; j < 4; ++j) {
            float sp_p, sp_m, sig;
            bce_pieces(xv[j], sp_p, sp_m, sig);
            float y = yv[j];
            As[j] += posv * y * sp_m;
            Cs[j] += posv * (1.0f - y) * sp_p;
            ss[j] += y;
            float om = 1.0f - sig;
            fs += om * om * y * (-sp_m);
            mymax = fmaxf(mymax, sig);
        }
        // group max over 8 cols = adjacent lane pair
        float gmax = fmaxf(mymax, __shfl_xor(mymax, 1, 64));
        if ((t & 1) == 0)
            hier += fmaxf(gmax - nsig, 0.0f) * posv;
    }

    // thread t uniquely owns its 4 sub cols within the block: direct store
    emit4(cw + WS_AS   + 4 * t, As[0], As[1], As[2], As[3], excl);
    emit4(cw + WS_CS   + 4 * t, Cs[0], Cs[1], Cs[2], Cs[3], excl);
    emit4(cw + WS_SSUM + 4 * t, ss[0], ss[1], ss[2], ss[3], excl);

    // scalar partials: wave shuffle reduce -> LDS -> thread 0
    #pragma unroll
    for (int off = 32; off; off >>= 1) {
        fn   += __shfl_down(fn,   off, 64);
        fs   += __shfl_down(fs,   off, 64);
        hier += __shfl_down(hier, off, 64);
    }
    if ((t & 63) == 0) {
        int w = t >> 6;
        ssc[w][0] = fn; ssc[w][1] = fs; ssc[w][2] = hier;
    }
    __syncthreads();
    if (t == 0) {
        float a = 0.f, b = 0.f, c = 0.f;
        #pragma unroll
        for (int w = 0; w < 4; ++w) { a += ssc[w][0]; b += ssc[w][1]; c += ssc[w][2]; }
        if (excl) {
            cw[WS_FN] = a; cw[WS_FS] = b; cw[WS_HIER] = c;
        } else {
            atomicAdd(cw + WS_FN, a); atomicAdd(cw + WS_FS, b); atomicAdd(cw + WS_HIER, c);
        }
    }
}

// reduce stage 1: chunk by sums copies [32*by, 32*(by+1)) -> tmp[by]
__global__ __launch_bounds__(256) void ncl_reduce1(const float* __restrict__ ws,
                                                   float* __restrict__ tmp,
                                                   int ncopies)
{
    const int e = blockIdx.x * 256 + threadIdx.x;
    if (e >= WS_FLOATS) return;
    const int c0 = blockIdx.y * NCHUNK_MAX;
    const int c1 = min(c0 + NCHUNK_MAX, ncopies);
    float s = 0.f;
    for (int c = c0; c < c1; ++c)
        s += ws[(size_t)c * CSTRIDE + e];
    tmp[(size_t)blockIdx.y * CSTRIDE + e] = s;
}

// reduce stage 2: sum the chunk tables -> red
__global__ __launch_bounds__(256) void ncl_reduce2(const float* __restrict__ tmp,
                                                   float* __restrict__ red,
                                                   int nchunks)
{
    const int e = blockIdx.x * 256 + threadIdx.x;
    if (e >= WS_FLOATS) return;
    float s = 0.f;
    for (int c = 0; c < nchunks; ++c)
        s += tmp[(size_t)c * CSTRIDE + e];
    red[e] = s;
}

__global__ __launch_bounds__(1024) void ncl_finalize(const float* __restrict__ ws,
                                                     float* __restrict__ out)
{
    __shared__ float sr[3][16];
    const int t = threadIdx.x;
    const float Bf = (float)NROWS;

    float s_sub = ws[WS_SSUM + t];
    float spw   = fminf(fmaxf((Bf - s_sub) / (s_sub + 1e-6f), 1.0f), 50.0f);
    float sub_part = spw * ws[WS_AS + t] + ws[WS_CS + t];

    float narr_part = 0.f, valid_part = 0.f;
    if (t < NNARR) {
        float s = ws[WS_NSUM + t];
        float npw = fminf(fmaxf((Bf - s) / (s + 1e-6f), 1.0f), 50.0f);
        narr_part  = npw * ws[WS_AN + t] + ws[WS_CN + t];
        valid_part = s;
    }

    #pragma unroll
    for (int off = 32; off; off >>= 1) {
        sub_part   += __shfl_down(sub_part,   off, 64);
        narr_part  += __shfl_down(narr_part,  off, 64);
        valid_part += __shfl_down(valid_part, off, 64);
    }
    if ((t & 63) == 0) {
        int w = t >> 6;
        sr[0][w] = sub_part; sr[1][w] = narr_part; sr[2][w] = valid_part;
    }
    __syncthreads();
    if (t == 0) {
        float sub_tot = 0.f, narr_tot = 0.f, valid = 0.f;
        #pragma unroll
        for (int i = 0; i < 16; ++i) { sub_tot += sr[0][i]; narr_tot += sr[1][i]; valid += sr[2][i]; }

        float narrative_loss = narr_tot / (Bf * (float)NNARR);
        float sub_loss = (valid > 0.0f) ? (sub_tot * (1.0f / 8.0f)) / fmaxf(valid, 1.0f) : 0.0f;
        float nf = ws[WS_FN] / (Bf * (float)NNARR);
        float sf = ws[WS_FS] / (Bf * (float)NSUB);
        float hier_loss = ws[WS_HIER] / Bf;

        out[0] = (narrative_loss - 0.1f * nf)
               + (sub_loss       - 0.1f * sf)
               + 0.5f * hier_loss;
    }
}

extern "C" void kernel_launch(void* const* d_in, const int* in_sizes, int n_in,
                              void* d_out, int out_size, void* d_ws, size_t ws_size,
                              hipStream_t stream) {
    const float* nlog = (const float*)d_in[0];
    const float* slog = (const float*)d_in[1];
    const int*   nlab = (const int*)d_in[2];
    const int*   slab = (const int*)d_in[3];
    float* ws  = (float*)d_ws;
    float* out = (float*)d_out;

    // ws layout: [ncopies copies][NCHUNK_MAX tmp tables][red table]
    long avail = (long)(ws_size / 4);
    long nc = avail / CSTRIDE - (NCHUNK_MAX + 1);
    int ncopies = (int)(nc < 1 ? 1 : (nc > NBLOCKS ? NBLOCKS : nc));
    int excl = (ncopies == NBLOCKS) ? 1 : 0;
    float* tmp = ws + (size_t)ncopies * CSTRIDE;
    float* red = tmp + (size_t)NCHUNK_MAX * CSTRIDE;
    int nchunks = (ncopies + NCHUNK_MAX - 1) / NCHUNK_MAX;

    if (!excl)
        hipMemsetAsync(ws, 0, (size_t)ncopies * CSTRIDE * sizeof(float), stream);

    ncl_main<<<NBLOCKS, BDIM, 0, stream>>>(nlog, slog, nlab, slab, ws, ncopies, excl);

    dim3 g1((WS_FLOATS + 255) / 256, nchunks);
    ncl_reduce1<<<g1, 256, 0, stream>>>(ws, tmp, ncopies);
    ncl_reduce2<<<(WS_FLOATS + 255) / 256, 256, 0, stream>>>(tmp, red, nchunks);
    ncl_finalize<<<1, 1024, 0, stream>>>(red, out);
}